// Round 15
// baseline (589.644 us; speedup 1.0000x reference)
//
#include <hip/hip_runtime.h>

#define L 50
#define NA 120
#define NB 8
#define NPIX 2500
#define NFREQ 51
#define NFULL 100
#define IST 52                 // F1 global inner stride (16B-aligned)
#define ISPEC (NFULL * IST)    // 5200 float2 per F1 spectrum
#define PST 51                 // inv LDS inner stride (Pl = 100*51 f2 = 40800 B)
#define RST 53                 // fwd_rec LDS inner stride
#define AST 51                 // fwd_prod Arow stride (52 rows, rows 50-51 zero)
#define ASTEP 0.026179938779914944f   // pi/120
#define PHI   0.06283185307179586f    // 2*pi/100

// workspace layout in floats
#define OFF_REC  0                    // 8*2*2500 = 40000
#define OFF_LIG  40000                // 40000
#define OFF_F1   80000                // 16 * 5200 f2 = 166400 floats
#define OFF_P2   246400               // 960 * 5100 f2 = 9792000 floats
#define OFF_PVAL 11766400             // 960
#define OFF_PIDX 11767360             // 960

#define CROT(wx, wy, sx, sy) { float nx_ = fmaf(wx, sx, -(wy) * (sy)); \
                               float ny_ = fmaf(wx, sy,  (wy) * (sx)); \
                               wx = nx_; wy = ny_; }
// complex MAC: acc += q * w
#define CMAC(q, wx, wy, ax, ay) { ax = fmaf(q.x, wx, fmaf(-q.y, wy, ax)); \
                                  ay = fmaf(q.x, wy, fmaf( q.y, wx, ay)); }

// ---------------- conv 3x3 (SAME) + bias; ligand channels combined with
// scorer weights (linearity: rotate/FFT commute with the real combine) ------
__global__ __launch_bounds__(256) void k_conv(
    const float* __restrict__ rec, const float* __restrict__ lig,
    const float* __restrict__ cw, const float* __restrict__ cb,
    const float* __restrict__ sw,
    float* __restrict__ rec_feat, float* __restrict__ lig_comb) {
  int t = blockIdx.x * blockDim.x + threadIdx.x;
  if (t >= NB * NPIX) return;
  int b = t / NPIX, p = t % NPIX;
  int i = p / L, j = p % L;
  float r0 = cb[0], r1 = cb[1], l0 = cb[0], l1 = cb[1];
  for (int di = 0; di < 3; ++di) {
    int ii = i + di - 1;
    if (ii < 0 || ii >= L) continue;
    for (int dj = 0; dj < 3; ++dj) {
      int jj = j + dj - 1;
      if (jj < 0 || jj >= L) continue;
      float w0 = cw[di * 3 + dj], w1 = cw[9 + di * 3 + dj];
      float xv = rec[b * NPIX + ii * L + jj];
      float yv = lig[b * NPIX + ii * L + jj];
      r0 += w0 * xv; r1 += w1 * xv;
      l0 += w0 * yv; l1 += w1 * yv;
    }
  }
  rec_feat[(b * 2 + 0) * NPIX + p] = r0;
  rec_feat[(b * 2 + 1) * NPIX + p] = r1;
  lig_comb[(b * 2 + 0) * NPIX + p] = sw[0] * l0 + sw[1] * l1;
  lig_comb[(b * 2 + 1) * NPIX + p] = sw[2] * l0 + sw[3] * l1;
}

// ---- rowDFT: Arow[r][k] = sum_c img[r][c] e^{-i*PHI*k*c}; 10 rows/thread ---
__device__ __forceinline__ void rowdft(const float* img, float2* Arow, int tid,
                                       int stride) {
  if (tid < 255) {
    const int kR = tid % 51, rgR = tid / 51;   // rows rgR + 5t, t<10
    float are[10], aim[10];
#pragma unroll
    for (int t = 0; t < 10; ++t) { are[t] = 0.f; aim[t] = 0.f; }
    float stx, sty;
    sincosf(PHI * (float)kR, &sty, &stx); sty = -sty;
    for (int half = 0; half < 2; ++half) {
      int u0 = half ? 6 : 0, u1 = half ? 13 : 6;
      float wx, wy;
      int t0 = half ? (24 * kR) % 100 : 0;
      sincosf(PHI * (float)t0, &wy, &wx); wy = -wy;
      for (int u = u0; u < u1; ++u) {
        float4 q[10];
#pragma unroll
        for (int t = 0; t < 10; ++t)
          q[t] = *(const float4*)(img + (rgR + 5 * t) * 52 + 4 * u);
#pragma unroll
        for (int v = 0; v < 4; ++v) {
#pragma unroll
          for (int t = 0; t < 10; ++t) {
            float val = (v == 0) ? q[t].x : (v == 1) ? q[t].y : (v == 2) ? q[t].z : q[t].w;
            are[t] = fmaf(val, wx, are[t]);
            aim[t] = fmaf(val, wy, aim[t]);
          }
          CROT(wx, wy, stx, sty);
        }
      }
    }
#pragma unroll
    for (int t = 0; t < 10; ++t)
      Arow[(rgR + 5 * t) * stride + kR] = make_float2(are[t], aim[t]);
  }
}

// ---------------- forward rfft2 of receptor channels: 16 images x 5 k-chunks
// per block (80 blocks). colDFT radix-2 over 250 lanes, <=3 cols. -----------
__global__ __launch_bounds__(256, 3) void k_fwd_rec(
    const float* __restrict__ src, float2* __restrict__ F1w) {
  __shared__ __align__(16) float img[50 * 52];
  __shared__ __align__(16) float2 Arow[50 * RST + 8];
  const int tid = threadIdx.x;
  const int im = blockIdx.x % 16, kcB = blockIdx.x / 16;   // 5 chunks
  const int k0 = (kcB == 0) ? 0 : 11 + 10 * (kcB - 1);
  for (int o = tid; o < 50 * 52; o += 256) {
    int i = o / 52, j = o - i * 52;
    img[o] = (j < 50) ? src[im * NPIX + i * 50 + j] : 0.f;
  }
  __syncthreads();
  rowdft(img, Arow, tid, RST);
  __syncthreads();
  if (tid < 250) {
    const int mp = tid % 50, sub = tid / 50;
    int c0, cw;
    if (kcB == 0) { cw = (sub == 0) ? 3 : 2; c0 = (sub == 0) ? 0 : 1 + 2 * sub; }
    else          { cw = 2; c0 = 2 * sub; }
    float Ex[3], Ey[3], Ox[3], Oy[3];
#pragma unroll
    for (int i = 0; i < 3; ++i) { Ex[i] = 0.f; Ey[i] = 0.f; Ox[i] = 0.f; Oy[i] = 0.f; }
    float s2x, s2y;
    sincosf(PHI * (float)((2 * mp) % 100), &s2y, &s2x); s2y = -s2y;
    { float wx = 1.f, wy = 0.f;
      for (int s = 0; s < 25; ++s) {
        const float2* ap = Arow + (2 * s) * RST + k0 + c0;
#pragma unroll
        for (int i = 0; i < 3; ++i) { float2 q = ap[i]; CMAC(q, wx, wy, Ex[i], Ey[i]); }
        CROT(wx, wy, s2x, s2y);
      } }
    { float wx, wy;
      sincosf(PHI * (float)mp, &wy, &wx); wy = -wy;
      for (int s = 0; s < 25; ++s) {
        const float2* ap = Arow + (2 * s + 1) * RST + k0 + c0;
#pragma unroll
        for (int i = 0; i < 3; ++i) { float2 q = ap[i]; CMAC(q, wx, wy, Ox[i], Oy[i]); }
        CROT(wx, wy, s2x, s2y);
      } }
    float2* d0 = F1w + (size_t)im * ISPEC + mp * IST + k0 + c0;
    float2* d1 = d0 + 50 * IST;
#pragma unroll
    for (int i = 0; i < 3; ++i)
      if (i < cw) {
        d0[i] = make_float2(Ex[i] + Ox[i], Ey[i] + Oy[i]);
        d1[i] = make_float2(Ex[i] - Ox[i], Ey[i] - Oy[i]);
      }
  }
}

// ---------------- per-(angle,batch): rotate(x2) -> rowDFT(x2) -> colDFT
// RADIX-4 over r mod 4 + product for both channels -> packed P write. -------
// P2 layout: [ab][vlane 0..424][12 float2]; vlane v: mp=v%25, c=v/25 (17
// chunks of 3 k-cols, k0=3c); float4 slot i*2 = (P[mp][k0+i], P[mp+25][k0+i]),
// slot i*2+1 = (P[mp+50][k0+i], P[mp+75][k0+i]).
__global__ __launch_bounds__(256, 3) void k_fwd_prod(
    const float* __restrict__ lig_comb, const float2* __restrict__ F1,
    float2* __restrict__ P2) {
  __shared__ __align__(16) float img[50 * 52];          // 10.4 KB
  __shared__ __align__(16) float2 Arow[2][52 * AST];    // 42.4 KB (rows 50-51 zero)
  const int tid = threadIdx.x;
  const int ab = blockIdx.x, a = ab / NB, b = ab % NB;
  float sa, ca; sincosf((float)a * ASTEP, &sa, &ca);

  // zero pad rows 50,51 of both channels (persist across f: rowdft writes 0..49)
  for (int o = tid; o < 2 * 2 * AST; o += 256) {
    int f = o / (2 * AST), rem = o % (2 * AST);
    Arow[f][50 * AST + rem] = make_float2(0.f, 0.f);
  }

  for (int f = 0; f < 2; ++f) {
    const float* src = lig_comb + (b * 2 + f) * NPIX;
    for (int o = tid; o < 50 * 52; o += 256) {
      int i = o / 52, j = o - i * 52;
      float acc = 0.f;
      if (j < 50) {
        float gx = fmaf((float)j, 2.0f / 49.0f, -1.0f);
        float gy = fmaf((float)i, 2.0f / 49.0f, -1.0f);
        float ix = (ca * gx + sa * gy + 1.0f) * 24.5f;
        float iy = (ca * gy - sa * gx + 1.0f) * 24.5f;
        float x0 = floorf(ix), y0 = floorf(iy);
#pragma unroll
        for (int dy = 0; dy < 2; ++dy)
#pragma unroll
          for (int dx = 0; dx < 2; ++dx) {
            float xc = x0 + dx, yc = y0 + dy;
            float w = (1.0f - fabsf(ix - xc)) * (1.0f - fabsf(iy - yc));
            bool valid = (xc >= 0.f) && (xc < 50.f) && (yc >= 0.f) && (yc < 50.f);
            int xi = (int)fminf(fmaxf(xc, 0.f), 49.f);
            int yi = (int)fminf(fmaxf(yc, 0.f), 49.f);
            acc += valid ? w * src[yi * L + xi] : 0.f;
          }
      }
      img[o] = acc;
    }
    __syncthreads();
    rowdft(img, Arow[f], tid, AST);
    __syncthreads();
  }

  // colDFT radix-4 + product, 2 passes (425 vlanes). Q index q = ch*3 + i.
  for (int pass = 0; pass < 2; ++pass) {
    const int v = pass * 256 + tid;
    if (v < 425) {
      const int mp = v % 25, c = v / 25;   // c in [0,17)
      const int k0 = 3 * c;
      float Q0x[6], Q0y[6], Q1x[6], Q1y[6], Q2x[6], Q2y[6], Q3x[6], Q3y[6];
#pragma unroll
      for (int q = 0; q < 6; ++q) {
        Q0x[q] = 0.f; Q0y[q] = 0.f; Q1x[q] = 0.f; Q1y[q] = 0.f;
        Q2x[q] = 0.f; Q2y[q] = 0.f; Q3x[q] = 0.f; Q3y[q] = 0.f;
      }
      float s4x, s4y;                      // step e^{-i 4 phi mp}
      sincosf(PHI * (float)((4 * mp) % 100), &s4y, &s4x); s4y = -s4y;
      float wx = 1.f, wy = 0.f;
      for (int s = 0; s < 13; ++s) {       // rows 4s+j; 50,51 are zero pad
        const float2* b0 = &Arow[0][(4 * s) * AST + k0];
        const float2* b1 = &Arow[1][(4 * s) * AST + k0];
#pragma unroll
        for (int i = 0; i < 3; ++i) {
          float2 q;
          q = b0[i];           CMAC(q, wx, wy, Q0x[i],     Q0y[i]);
          q = b0[AST + i];     CMAC(q, wx, wy, Q1x[i],     Q1y[i]);
          q = b0[2*AST + i];   CMAC(q, wx, wy, Q2x[i],     Q2y[i]);
          q = b0[3*AST + i];   CMAC(q, wx, wy, Q3x[i],     Q3y[i]);
          q = b1[i];           CMAC(q, wx, wy, Q0x[3 + i], Q0y[3 + i]);
          q = b1[AST + i];     CMAC(q, wx, wy, Q1x[3 + i], Q1y[3 + i]);
          q = b1[2*AST + i];   CMAC(q, wx, wy, Q2x[3 + i], Q2y[3 + i]);
          q = b1[3*AST + i];   CMAC(q, wx, wy, Q3x[3 + i], Q3y[3 + i]);
        }
        CROT(wx, wy, s4x, s4y);
      }
      // combine: u_j = e^{-i phi j mp} Q_j; G[mp+25t] = sum_j (-i)^{tj} u_j
      float c1x, c1y; sincosf(PHI * (float)mp, &c1y, &c1x); c1y = -c1y;
      float c2x = fmaf(c1x, c1x, -c1y * c1y), c2y = 2.f * c1x * c1y;
      float c3x = fmaf(c2x, c1x, -c2y * c1y), c3y = fmaf(c2x, c1y, c2y * c1x);
      float4* dst = (float4*)(P2 + (size_t)ab * 5100 + v * 12);
#pragma unroll
      for (int i = 0; i < 3; ++i) {
        float px[4], py[4];
#pragma unroll
        for (int t = 0; t < 4; ++t) { px[t] = 0.f; py[t] = 0.f; }
#pragma unroll
        for (int ch = 0; ch < 2; ++ch) {
          const int q = ch * 3 + i;
          float u0x = Q0x[q], u0y = Q0y[q];
          float u1x = fmaf(c1x, Q1x[q], -c1y * Q1y[q]);
          float u1y = fmaf(c1x, Q1y[q],  c1y * Q1x[q]);
          float u2x = fmaf(c2x, Q2x[q], -c2y * Q2y[q]);
          float u2y = fmaf(c2x, Q2y[q],  c2y * Q2x[q]);
          float u3x = fmaf(c3x, Q3x[q], -c3y * Q3y[q]);
          float u3y = fmaf(c3x, Q3y[q],  c3y * Q3x[q]);
          float Axx = u0x + u2x, Ayy = u0y + u2y;
          float Bxx = u0x - u2x, Byy = u0y - u2y;
          float Cxx = u1x + u3x, Cyy = u1y + u3y;
          float Dxx = u1x - u3x, Dyy = u1y - u3y;
          float Gx[4], Gy[4];
          Gx[0] = Axx + Cxx; Gy[0] = Ayy + Cyy;
          Gx[2] = Axx - Cxx; Gy[2] = Ayy - Cyy;
          Gx[1] = Bxx + Dyy; Gy[1] = Byy - Dxx;   // B - iD
          Gx[3] = Bxx - Dyy; Gy[3] = Byy + Dxx;   // B + iD
          const float2* Fb = F1 + (size_t)(b * 2 + ch) * ISPEC + mp * IST + k0 + i;
#pragma unroll
          for (int t = 0; t < 4; ++t) {
            float2 Fv = Fb[t * 25 * IST];
            px[t] = fmaf(Fv.x, Gx[t], fmaf( Fv.y, Gy[t], px[t]));
            py[t] = fmaf(Fv.y, Gx[t], fmaf(-Fv.x, Gy[t], py[t]));
          }
        }
        dst[i * 2 + 0] = make_float4(px[0], py[0], px[1], py[1]);
        dst[i * 2 + 1] = make_float4(px[2], py[2], px[3], py[3]);
      }
    }
  }
}

// ---------------- inverse: stage 1 RADIX-4 (R13-verified); stage 2 dual-cp
// (cp, cp+25) via 25-shift symmetry with s-parity-split accumulation —
// halves stage-2 LDS reads AND FMAs per output. Reduction via shuffles. -----
__global__ __launch_bounds__(256, 4) void k_inv_argmax(
    const float2* __restrict__ P2, float* __restrict__ pval,
    int* __restrict__ pidx) {
  __shared__ __align__(16) float2 Pl[100 * PST];   // P[m][k]; later T[k][100]
  __shared__ float wr[4];
  __shared__ int wi[4];
  const int tid = threadIdx.x, ab = blockIdx.x;

  // un-pack radix-4 packed P into Pl[m*PST + k]
  for (int h = 0; h < 2; ++h) {
    const int v = h * 256 + tid;
    if (v < 425) {
      const int mp = v % 25, c = v / 25, kk = 3 * c;
      const float4* s4 = (const float4*)(P2 + (size_t)ab * 5100 + v * 12);
#pragma unroll
      for (int i = 0; i < 3; ++i) {
        float4 q01 = s4[i * 2], q23 = s4[i * 2 + 1];
        Pl[(mp     ) * PST + kk + i] = make_float2(q01.x, q01.y);
        Pl[(mp + 25) * PST + kk + i] = make_float2(q01.z, q01.w);
        Pl[(mp + 50) * PST + kk + i] = make_float2(q23.x, q23.y);
        Pl[(mp + 75) * PST + kk + i] = make_float2(q23.z, q23.w);
      }
    }
  }
  __syncthreads();

  // stage 1 radix-4: T[rp+25t][k] = sum_j i^{tj} (c1^j Q_j[k]),
  // Q_j[k] = sum_s P[4s+j][k] e^{+i 4 phi s rp}
  const int rp = tid % 25, kc = tid / 25;   // kc in [0,8), tid<200
  const int k0 = (kc < 3) ? 7 * kc : 21 + 6 * (kc - 3);
  const int CW = (kc < 3) ? 7 : 6;
  float Q0x[7], Q0y[7], Q1x[7], Q1y[7], Q2x[7], Q2y[7], Q3x[7], Q3y[7];
  if (tid < 200) {
#pragma unroll
    for (int q = 0; q < 7; ++q) {
      Q0x[q] = 0.f; Q0y[q] = 0.f; Q1x[q] = 0.f; Q1y[q] = 0.f;
      Q2x[q] = 0.f; Q2y[q] = 0.f; Q3x[q] = 0.f; Q3y[q] = 0.f;
    }
    float s4x, s4y;                          // step e^{+i 4 phi rp}
    sincosf(PHI * (float)((4 * rp) % 100), &s4y, &s4x);
    float wx = 1.f, wy = 0.f;
    for (int s = 0; s < 25; ++s) {
      const float2* p0 = Pl + (4 * s) * PST + k0;
#pragma unroll
      for (int i = 0; i < 7; ++i) {
        float2 q;
        q = p0[i];           CMAC(q, wx, wy, Q0x[i], Q0y[i]);
        q = p0[PST + i];     CMAC(q, wx, wy, Q1x[i], Q1y[i]);
        q = p0[2*PST + i];   CMAC(q, wx, wy, Q2x[i], Q2y[i]);
        q = p0[3*PST + i];   CMAC(q, wx, wy, Q3x[i], Q3y[i]);
      }
      CROT(wx, wy, s4x, s4y);
    }
  }
  __syncthreads();   // ALL P reads done; safe to overwrite Pl with T
  if (tid < 200) {
    float c1x, c1y; sincosf(PHI * (float)rp, &c1y, &c1x);   // e^{+i phi rp}
    float c2x = fmaf(c1x, c1x, -c1y * c1y), c2y = 2.f * c1x * c1y;
    float c3x = fmaf(c2x, c1x, -c2y * c1y), c3y = fmaf(c2x, c1y, c2y * c1x);
#pragma unroll
    for (int i = 0; i < 7; ++i) {
      float u1x = fmaf(c1x, Q1x[i], -c1y * Q1y[i]);
      float u1y = fmaf(c1x, Q1y[i],  c1y * Q1x[i]);
      float u2x = fmaf(c2x, Q2x[i], -c2y * Q2y[i]);
      float u2y = fmaf(c2x, Q2y[i],  c2y * Q2x[i]);
      float u3x = fmaf(c3x, Q3x[i], -c3y * Q3y[i]);
      float u3y = fmaf(c3x, Q3y[i],  c3y * Q3x[i]);
      float Axx = Q0x[i] + u2x, Ayy = Q0y[i] + u2y;
      float Bxx = Q0x[i] - u2x, Byy = Q0y[i] - u2y;
      float Cxx = u1x + u3x,    Cyy = u1y + u3y;
      float Dxx = u1x - u3x,    Dyy = u1y - u3y;
      if (i < CW) {
        float2* Tk = Pl + (k0 + i) * NFULL;
        Tk[rp]      = make_float2(Axx + Cxx, Ayy + Cyy);
        Tk[rp + 25] = make_float2(Bxx - Dyy, Byy + Dxx);   // B + iD
        Tk[rp + 50] = make_float2(Axx - Cxx, Ayy - Cyy);
        Tk[rp + 75] = make_float2(Bxx + Dyy, Byy - Dxx);   // B - iD
      }
    }
  }
  __syncthreads();   // T[k][r] ready (transposed)

  // stage 2 dual-cp: lane (cp in [0,25), rc8 in [0,8)) covers columns
  // cp, cp+25, cp+50, cp+75 for r-chunk r0..r0+RW-1.
  // Even k=2s: twiddle(cp+25) = (-1)^s twiddle(cp); odd k=2s+1:
  // twiddle(cp+25) = (-1)^s * i * twiddle(cp)  ->  s-parity-split sums.
  float best = -3.4e38f;
  int bidx = 0x7fffffff;
  if (tid < 200) {
    const int cp = tid % 25, rc8 = tid / 25;
    const int r0 = (rc8 < 6) ? 12 * rc8 : 72 + 14 * (rc8 - 6);  // even starts
    const int RW = (rc8 < 6) ? 12 : 14;
    float SP[14], SM[14], OPre[14], OPim[14], OMre[14], OMim[14];
#pragma unroll
    for (int i = 0; i < 14; ++i) {
      SP[i] = 0.f; SM[i] = 0.f; OPre[i] = 0.f;
      OPim[i] = 0.f; OMre[i] = 0.f; OMim[i] = 0.f;
    }
    float stx, sty;
    sincosf(PHI * (float)((2 * cp) % 100), &sty, &stx);   // step e^{+2i phi cp}
    // even-k part: k=2s, s=1..24; odd s -> SM, even s -> SP (real parts only)
    { float wx = stx, wy = sty;                            // s=1
      for (int s2 = 0; s2 < 12; ++s2) {
        const float4* tpA = (const float4*)(Pl + (4 * s2 + 2) * NFULL + r0);
#pragma unroll
        for (int h = 0; h < 7; ++h) {
          float4 q = tpA[h];
          SM[2*h]   = fmaf(q.x, wx, fmaf(-q.y, wy, SM[2*h]));
          SM[2*h+1] = fmaf(q.z, wx, fmaf(-q.w, wy, SM[2*h+1]));
        }
        CROT(wx, wy, stx, sty);
        const float4* tpB = (const float4*)(Pl + (4 * s2 + 4) * NFULL + r0);
#pragma unroll
        for (int h = 0; h < 7; ++h) {
          float4 q = tpB[h];
          SP[2*h]   = fmaf(q.x, wx, fmaf(-q.y, wy, SP[2*h]));
          SP[2*h+1] = fmaf(q.z, wx, fmaf(-q.w, wy, SP[2*h+1]));
        }
        CROT(wx, wy, stx, sty);
      } }
    // odd-k part: k=2s+1, s=0..24; even s -> OP, odd s -> OM (re+im)
    { float wx, wy;
      sincosf(PHI * (float)cp, &wy, &wx);                  // s=0 (k=1)
      for (int s2 = 0; s2 < 12; ++s2) {
        const float4* tpA = (const float4*)(Pl + (4 * s2 + 1) * NFULL + r0);
#pragma unroll
        for (int h = 0; h < 7; ++h) {
          float4 q = tpA[h];
          OPre[2*h]   = fmaf(q.x, wx, fmaf(-q.y, wy, OPre[2*h]));
          OPim[2*h]   = fmaf(q.x, wy, fmaf( q.y, wx, OPim[2*h]));
          OPre[2*h+1] = fmaf(q.z, wx, fmaf(-q.w, wy, OPre[2*h+1]));
          OPim[2*h+1] = fmaf(q.z, wy, fmaf( q.w, wx, OPim[2*h+1]));
        }
        CROT(wx, wy, stx, sty);
        const float4* tpB = (const float4*)(Pl + (4 * s2 + 3) * NFULL + r0);
#pragma unroll
        for (int h = 0; h < 7; ++h) {
          float4 q = tpB[h];
          OMre[2*h]   = fmaf(q.x, wx, fmaf(-q.y, wy, OMre[2*h]));
          OMim[2*h]   = fmaf(q.x, wy, fmaf( q.y, wx, OMim[2*h]));
          OMre[2*h+1] = fmaf(q.z, wx, fmaf(-q.w, wy, OMre[2*h+1]));
          OMim[2*h+1] = fmaf(q.z, wy, fmaf( q.w, wx, OMim[2*h+1]));
        }
        CROT(wx, wy, stx, sty);
      }
      // tail s=24 (even) -> OP, k=49
      { const float4* tp = (const float4*)(Pl + 49 * NFULL + r0);
#pragma unroll
        for (int h = 0; h < 7; ++h) {
          float4 q = tp[h];
          OPre[2*h]   = fmaf(q.x, wx, fmaf(-q.y, wy, OPre[2*h]));
          OPim[2*h]   = fmaf(q.x, wy, fmaf( q.y, wx, OPim[2*h]));
          OPre[2*h+1] = fmaf(q.z, wx, fmaf(-q.w, wy, OPre[2*h+1]));
          OPim[2*h+1] = fmaf(q.z, wy, fmaf( q.w, wx, OPim[2*h+1]));
        }
      } }
    float sgn0 = (cp & 1) ? -1.f : 1.f;
    const float2* T0  = Pl + r0;
    const float2* T50 = Pl + 50 * NFULL + r0;
#pragma unroll
    for (int i = 0; i < 14; ++i)
      if (i < RW) {
        int r = r0 + i;
        float t0x = T0[i].x, t50x = sgn0 * T50[i].x;
        float b0 = t0x + t50x;      // c = cp, cp+50
        float b1 = t0x - t50x;      // c = cp+25, cp+75
        float e0 = SP[i] + SM[i],   e1 = SP[i] - SM[i];
        float o0 = OPre[i] + OMre[i];
        float o1 = OMim[i] - OPim[i];
        float X0 = fmaf(2.f, e0 + o0, b0);   // c = cp
        float X1 = fmaf(2.f, e0 - o0, b0);   // c = cp + 50
        float X2 = fmaf(2.f, e1 + o1, b1);   // c = cp + 25
        float X3 = fmaf(2.f, e1 - o1, b1);   // c = cp + 75
        int xs = r + 50; if (xs >= 100) xs -= 100;
        int g0 = xs * 100 + cp + 50;
        int g1 = xs * 100 + cp;
        int g2 = xs * 100 + cp + 75;
        int g3 = xs * 100 + cp + 25;
        if (X0 > best || (X0 == best && g0 < bidx)) { best = X0; bidx = g0; }
        if (X1 > best || (X1 == best && g1 < bidx)) { best = X1; bidx = g1; }
        if (X2 > best || (X2 == best && g2 < bidx)) { best = X2; bidx = g2; }
        if (X3 > best || (X3 == best && g3 < bidx)) { best = X3; bidx = g3; }
      }
  }
  // wave-level shuffle reduction (64 lanes), then cross-wave via 4-entry LDS
  for (int off = 32; off > 0; off >>= 1) {
    float ov = __shfl_down(best, off);
    int oi = __shfl_down(bidx, off);
    if (ov > best || (ov == best && oi < bidx)) { best = ov; bidx = oi; }
  }
  if ((tid & 63) == 0) { wr[tid >> 6] = best; wi[tid >> 6] = bidx; }
  __syncthreads();
  if (tid == 0) {
#pragma unroll
    for (int w = 1; w < 4; ++w) {
      if (wr[w] > best || (wr[w] == best && wi[w] < bidx)) { best = wr[w]; bidx = wi[w]; }
    }
    pval[ab] = best; pidx[ab] = (ab / NB) * 10000 + bidx;
  }
}

// ---------------- final per-batch reduction over 120 angles ----------------
__global__ void k_final(const float* __restrict__ pval,
                        const int* __restrict__ pidx, float* __restrict__ out) {
  int b = threadIdx.x;
  if (b >= NB) return;
  float best = -3.4e38f; int bidx = 0x7fffffff;
  for (int a = 0; a < NA; ++a) {
    float v = pval[a * NB + b]; int ix = pidx[a * NB + b];
    if (v > best || (v == best && ix < bidx)) { best = v; bidx = ix; }
  }
  int a = bidx / 10000, rr = bidx % 10000, x = rr / NFULL, y = rr % NFULL;
  out[b] = a * ASTEP;
  out[NB + b * 2 + 0] = (float)(x - L);
  out[NB + b * 2 + 1] = (float)(y - L);
}

extern "C" void kernel_launch(void* const* d_in, const int* in_sizes, int n_in,
                              void* d_out, int out_size, void* d_ws, size_t ws_size,
                              hipStream_t stream) {
  const float* receptor = (const float*)d_in[0];
  const float* ligand   = (const float*)d_in[1];
  const float* conv_w   = (const float*)d_in[2];
  const float* conv_b   = (const float*)d_in[3];
  const float* scorer_w = (const float*)d_in[4];
  // scorer_b (d_in[5]) is argmax-invariant: unused.
  float* ws = (float*)d_ws;
  float* rec_feat = ws + OFF_REC;
  float* lig_comb = ws + OFF_LIG;
  float2* F1      = (float2*)(ws + OFF_F1);
  float2* P2      = (float2*)(ws + OFF_P2);
  float* pval     = ws + OFF_PVAL;
  int*   pidx     = (int*)(ws + OFF_PIDX);
  float* out      = (float*)d_out;

  k_conv<<<(NB * NPIX + 255) / 256, 256, 0, stream>>>(
      receptor, ligand, conv_w, conv_b, scorer_w, rec_feat, lig_comb);
  k_fwd_rec<<<80, 256, 0, stream>>>(rec_feat, F1);
  k_fwd_prod<<<NA * NB, 256, 0, stream>>>(lig_comb, F1, P2);
  k_inv_argmax<<<NA * NB, 256, 0, stream>>>(P2, pval, pidx);
  k_final<<<1, 64, 0, stream>>>(pval, pidx, out);
}

// Round 16
// 244.210 us; speedup vs baseline: 2.4145x; 2.4145x over previous
//
#include <hip/hip_runtime.h>

#define L 50
#define NA 120
#define NB 8
#define NPIX 2500
#define NFREQ 51
#define NFULL 100
#define IST 52                 // F1 global inner stride (16B-aligned)
#define ISPEC (NFULL * IST)    // 5200 float2 per F1 spectrum
#define PST 51                 // inv LDS inner stride (Pl = 100*51 f2 = 40800 B)
#define RST 53                 // fwd_rec LDS inner stride
#define AST 51                 // fwd_prod Arow stride (52 rows, rows 50-51 zero)
#define ASTEP 0.026179938779914944f   // pi/120
#define PHI   0.06283185307179586f    // 2*pi/100

// workspace layout in floats
#define OFF_REC  0                    // 8*2*2500 = 40000
#define OFF_LIG  40000                // 40000
#define OFF_F1   80000                // 16 * 5200 f2 = 166400 floats
#define OFF_P2   246400               // 960 * 5100 f2 = 9792000 floats
#define OFF_PVAL 11766400             // 960
#define OFF_PIDX 11767360             // 960

#define CROT(wx, wy, sx, sy) { float nx_ = fmaf(wx, sx, -(wy) * (sy)); \
                               float ny_ = fmaf(wx, sy,  (wy) * (sx)); \
                               wx = nx_; wy = ny_; }
// complex MAC: acc += q * w
#define CMAC(q, wx, wy, ax, ay) { ax = fmaf(q.x, wx, fmaf(-q.y, wy, ax)); \
                                  ay = fmaf(q.x, wy, fmaf( q.y, wx, ay)); }

// ---------------- conv 3x3 (SAME) + bias; ligand channels combined with
// scorer weights (linearity: rotate/FFT commute with the real combine) ------
__global__ __launch_bounds__(256) void k_conv(
    const float* __restrict__ rec, const float* __restrict__ lig,
    const float* __restrict__ cw, const float* __restrict__ cb,
    const float* __restrict__ sw,
    float* __restrict__ rec_feat, float* __restrict__ lig_comb) {
  int t = blockIdx.x * blockDim.x + threadIdx.x;
  if (t >= NB * NPIX) return;
  int b = t / NPIX, p = t % NPIX;
  int i = p / L, j = p % L;
  float r0 = cb[0], r1 = cb[1], l0 = cb[0], l1 = cb[1];
  for (int di = 0; di < 3; ++di) {
    int ii = i + di - 1;
    if (ii < 0 || ii >= L) continue;
    for (int dj = 0; dj < 3; ++dj) {
      int jj = j + dj - 1;
      if (jj < 0 || jj >= L) continue;
      float w0 = cw[di * 3 + dj], w1 = cw[9 + di * 3 + dj];
      float xv = rec[b * NPIX + ii * L + jj];
      float yv = lig[b * NPIX + ii * L + jj];
      r0 += w0 * xv; r1 += w1 * xv;
      l0 += w0 * yv; l1 += w1 * yv;
    }
  }
  rec_feat[(b * 2 + 0) * NPIX + p] = r0;
  rec_feat[(b * 2 + 1) * NPIX + p] = r1;
  lig_comb[(b * 2 + 0) * NPIX + p] = sw[0] * l0 + sw[1] * l1;
  lig_comb[(b * 2 + 1) * NPIX + p] = sw[2] * l0 + sw[3] * l1;
}

// ---- rowDFT: Arow[r][k] = sum_c img[r][c] e^{-i*PHI*k*c}; 10 rows/thread ---
__device__ __forceinline__ void rowdft(const float* img, float2* Arow, int tid,
                                       int stride) {
  if (tid < 255) {
    const int kR = tid % 51, rgR = tid / 51;   // rows rgR + 5t, t<10
    float are[10], aim[10];
#pragma unroll
    for (int t = 0; t < 10; ++t) { are[t] = 0.f; aim[t] = 0.f; }
    float stx, sty;
    sincosf(PHI * (float)kR, &sty, &stx); sty = -sty;
    for (int half = 0; half < 2; ++half) {
      int u0 = half ? 6 : 0, u1 = half ? 13 : 6;
      float wx, wy;
      int t0 = half ? (24 * kR) % 100 : 0;
      sincosf(PHI * (float)t0, &wy, &wx); wy = -wy;
      for (int u = u0; u < u1; ++u) {
        float4 q[10];
#pragma unroll
        for (int t = 0; t < 10; ++t)
          q[t] = *(const float4*)(img + (rgR + 5 * t) * 52 + 4 * u);
#pragma unroll
        for (int v = 0; v < 4; ++v) {
#pragma unroll
          for (int t = 0; t < 10; ++t) {
            float val = (v == 0) ? q[t].x : (v == 1) ? q[t].y : (v == 2) ? q[t].z : q[t].w;
            are[t] = fmaf(val, wx, are[t]);
            aim[t] = fmaf(val, wy, aim[t]);
          }
          CROT(wx, wy, stx, sty);
        }
      }
    }
#pragma unroll
    for (int t = 0; t < 10; ++t)
      Arow[(rgR + 5 * t) * stride + kR] = make_float2(are[t], aim[t]);
  }
}

// ---------------- forward rfft2 of receptor channels: 16 images x 5 k-chunks
// per block (80 blocks). colDFT radix-2 over 250 lanes, <=3 cols. -----------
__global__ __launch_bounds__(256, 3) void k_fwd_rec(
    const float* __restrict__ src, float2* __restrict__ F1w) {
  __shared__ __align__(16) float img[50 * 52];
  __shared__ __align__(16) float2 Arow[50 * RST + 8];
  const int tid = threadIdx.x;
  const int im = blockIdx.x % 16, kcB = blockIdx.x / 16;   // 5 chunks
  const int k0 = (kcB == 0) ? 0 : 11 + 10 * (kcB - 1);
  for (int o = tid; o < 50 * 52; o += 256) {
    int i = o / 52, j = o - i * 52;
    img[o] = (j < 50) ? src[im * NPIX + i * 50 + j] : 0.f;
  }
  __syncthreads();
  rowdft(img, Arow, tid, RST);
  __syncthreads();
  if (tid < 250) {
    const int mp = tid % 50, sub = tid / 50;
    int c0, cw;
    if (kcB == 0) { cw = (sub == 0) ? 3 : 2; c0 = (sub == 0) ? 0 : 1 + 2 * sub; }
    else          { cw = 2; c0 = 2 * sub; }
    float Ex[3], Ey[3], Ox[3], Oy[3];
#pragma unroll
    for (int i = 0; i < 3; ++i) { Ex[i] = 0.f; Ey[i] = 0.f; Ox[i] = 0.f; Oy[i] = 0.f; }
    float s2x, s2y;
    sincosf(PHI * (float)((2 * mp) % 100), &s2y, &s2x); s2y = -s2y;
    { float wx = 1.f, wy = 0.f;
      for (int s = 0; s < 25; ++s) {
        const float2* ap = Arow + (2 * s) * RST + k0 + c0;
#pragma unroll
        for (int i = 0; i < 3; ++i) { float2 q = ap[i]; CMAC(q, wx, wy, Ex[i], Ey[i]); }
        CROT(wx, wy, s2x, s2y);
      } }
    { float wx, wy;
      sincosf(PHI * (float)mp, &wy, &wx); wy = -wy;
      for (int s = 0; s < 25; ++s) {
        const float2* ap = Arow + (2 * s + 1) * RST + k0 + c0;
#pragma unroll
        for (int i = 0; i < 3; ++i) { float2 q = ap[i]; CMAC(q, wx, wy, Ox[i], Oy[i]); }
        CROT(wx, wy, s2x, s2y);
      } }
    float2* d0 = F1w + (size_t)im * ISPEC + mp * IST + k0 + c0;
    float2* d1 = d0 + 50 * IST;
#pragma unroll
    for (int i = 0; i < 3; ++i)
      if (i < cw) {
        d0[i] = make_float2(Ex[i] + Ox[i], Ey[i] + Oy[i]);
        d1[i] = make_float2(Ex[i] - Ox[i], Ey[i] - Oy[i]);
      }
  }
}

// ---------------- per-(angle,batch): rotate(x2) -> rowDFT(x2) -> colDFT
// RADIX-4 over r mod 4 + product for both channels -> packed P write. -------
// P2 layout: [ab][vlane 0..424][12 float2]; vlane v: mp=v%25, c=v/25 (17
// chunks of 3 k-cols, k0=3c); float4 slot i*2 = (P[mp][k0+i], P[mp+25][k0+i]),
// slot i*2+1 = (P[mp+50][k0+i], P[mp+75][k0+i]).
__global__ __launch_bounds__(256, 3) void k_fwd_prod(
    const float* __restrict__ lig_comb, const float2* __restrict__ F1,
    float2* __restrict__ P2) {
  __shared__ __align__(16) float img[50 * 52];          // 10.4 KB
  __shared__ __align__(16) float2 Arow[2][52 * AST];    // 42.4 KB (rows 50-51 zero)
  const int tid = threadIdx.x;
  const int ab = blockIdx.x, a = ab / NB, b = ab % NB;
  float sa, ca; sincosf((float)a * ASTEP, &sa, &ca);

  // zero pad rows 50,51 of both channels (persist across f: rowdft writes 0..49)
  for (int o = tid; o < 2 * 2 * AST; o += 256) {
    int f = o / (2 * AST), rem = o % (2 * AST);
    Arow[f][50 * AST + rem] = make_float2(0.f, 0.f);
  }

  for (int f = 0; f < 2; ++f) {
    const float* src = lig_comb + (b * 2 + f) * NPIX;
    for (int o = tid; o < 50 * 52; o += 256) {
      int i = o / 52, j = o - i * 52;
      float acc = 0.f;
      if (j < 50) {
        float gx = fmaf((float)j, 2.0f / 49.0f, -1.0f);
        float gy = fmaf((float)i, 2.0f / 49.0f, -1.0f);
        float ix = (ca * gx + sa * gy + 1.0f) * 24.5f;
        float iy = (ca * gy - sa * gx + 1.0f) * 24.5f;
        float x0 = floorf(ix), y0 = floorf(iy);
#pragma unroll
        for (int dy = 0; dy < 2; ++dy)
#pragma unroll
          for (int dx = 0; dx < 2; ++dx) {
            float xc = x0 + dx, yc = y0 + dy;
            float w = (1.0f - fabsf(ix - xc)) * (1.0f - fabsf(iy - yc));
            bool valid = (xc >= 0.f) && (xc < 50.f) && (yc >= 0.f) && (yc < 50.f);
            int xi = (int)fminf(fmaxf(xc, 0.f), 49.f);
            int yi = (int)fminf(fmaxf(yc, 0.f), 49.f);
            acc += valid ? w * src[yi * L + xi] : 0.f;
          }
      }
      img[o] = acc;
    }
    __syncthreads();
    rowdft(img, Arow[f], tid, AST);
    __syncthreads();
  }

  // colDFT radix-4 + product, 2 passes (425 vlanes). Q index q = ch*3 + i.
  for (int pass = 0; pass < 2; ++pass) {
    const int v = pass * 256 + tid;
    if (v < 425) {
      const int mp = v % 25, c = v / 25;   // c in [0,17)
      const int k0 = 3 * c;
      float Q0x[6], Q0y[6], Q1x[6], Q1y[6], Q2x[6], Q2y[6], Q3x[6], Q3y[6];
#pragma unroll
      for (int q = 0; q < 6; ++q) {
        Q0x[q] = 0.f; Q0y[q] = 0.f; Q1x[q] = 0.f; Q1y[q] = 0.f;
        Q2x[q] = 0.f; Q2y[q] = 0.f; Q3x[q] = 0.f; Q3y[q] = 0.f;
      }
      float s4x, s4y;                      // step e^{-i 4 phi mp}
      sincosf(PHI * (float)((4 * mp) % 100), &s4y, &s4x); s4y = -s4y;
      float wx = 1.f, wy = 0.f;
      for (int s = 0; s < 13; ++s) {       // rows 4s+j; 50,51 are zero pad
        const float2* b0 = &Arow[0][(4 * s) * AST + k0];
        const float2* b1 = &Arow[1][(4 * s) * AST + k0];
#pragma unroll
        for (int i = 0; i < 3; ++i) {
          float2 q;
          q = b0[i];           CMAC(q, wx, wy, Q0x[i],     Q0y[i]);
          q = b0[AST + i];     CMAC(q, wx, wy, Q1x[i],     Q1y[i]);
          q = b0[2*AST + i];   CMAC(q, wx, wy, Q2x[i],     Q2y[i]);
          q = b0[3*AST + i];   CMAC(q, wx, wy, Q3x[i],     Q3y[i]);
          q = b1[i];           CMAC(q, wx, wy, Q0x[3 + i], Q0y[3 + i]);
          q = b1[AST + i];     CMAC(q, wx, wy, Q1x[3 + i], Q1y[3 + i]);
          q = b1[2*AST + i];   CMAC(q, wx, wy, Q2x[3 + i], Q2y[3 + i]);
          q = b1[3*AST + i];   CMAC(q, wx, wy, Q3x[3 + i], Q3y[3 + i]);
        }
        CROT(wx, wy, s4x, s4y);
      }
      // combine: u_j = e^{-i phi j mp} Q_j; G[mp+25t] = sum_j (-i)^{tj} u_j
      float c1x, c1y; sincosf(PHI * (float)mp, &c1y, &c1x); c1y = -c1y;
      float c2x = fmaf(c1x, c1x, -c1y * c1y), c2y = 2.f * c1x * c1y;
      float c3x = fmaf(c2x, c1x, -c2y * c1y), c3y = fmaf(c2x, c1y, c2y * c1x);
      float4* dst = (float4*)(P2 + (size_t)ab * 5100 + v * 12);
#pragma unroll
      for (int i = 0; i < 3; ++i) {
        float px[4], py[4];
#pragma unroll
        for (int t = 0; t < 4; ++t) { px[t] = 0.f; py[t] = 0.f; }
#pragma unroll
        for (int ch = 0; ch < 2; ++ch) {
          const int q = ch * 3 + i;
          float u0x = Q0x[q], u0y = Q0y[q];
          float u1x = fmaf(c1x, Q1x[q], -c1y * Q1y[q]);
          float u1y = fmaf(c1x, Q1y[q],  c1y * Q1x[q]);
          float u2x = fmaf(c2x, Q2x[q], -c2y * Q2y[q]);
          float u2y = fmaf(c2x, Q2y[q],  c2y * Q2x[q]);
          float u3x = fmaf(c3x, Q3x[q], -c3y * Q3y[q]);
          float u3y = fmaf(c3x, Q3y[q],  c3y * Q3x[q]);
          float Axx = u0x + u2x, Ayy = u0y + u2y;
          float Bxx = u0x - u2x, Byy = u0y - u2y;
          float Cxx = u1x + u3x, Cyy = u1y + u3y;
          float Dxx = u1x - u3x, Dyy = u1y - u3y;
          float Gx[4], Gy[4];
          Gx[0] = Axx + Cxx; Gy[0] = Ayy + Cyy;
          Gx[2] = Axx - Cxx; Gy[2] = Ayy - Cyy;
          Gx[1] = Bxx + Dyy; Gy[1] = Byy - Dxx;   // B - iD
          Gx[3] = Bxx - Dyy; Gy[3] = Byy + Dxx;   // B + iD
          const float2* Fb = F1 + (size_t)(b * 2 + ch) * ISPEC + mp * IST + k0 + i;
#pragma unroll
          for (int t = 0; t < 4; ++t) {
            float2 Fv = Fb[t * 25 * IST];
            px[t] = fmaf(Fv.x, Gx[t], fmaf( Fv.y, Gy[t], px[t]));
            py[t] = fmaf(Fv.y, Gx[t], fmaf(-Fv.x, Gy[t], py[t]));
          }
        }
        dst[i * 2 + 0] = make_float4(px[0], py[0], px[1], py[1]);
        dst[i * 2 + 1] = make_float4(px[2], py[2], px[3], py[3]);
      }
    }
  }
}

// ---------------- inverse: stage 1 RADIX-4 (200 lanes, verified shape);
// stage 2 radix-2 with float4 T reads; wave-shuffle argmax reduction.
// LDS = 5100 f2 (40800 B) + 8-entry scratch -> 40960 B -> 4 blocks/CU. ------
__global__ __launch_bounds__(256, 4) void k_inv_argmax(
    const float2* __restrict__ P2, float* __restrict__ pval,
    int* __restrict__ pidx) {
  __shared__ __align__(16) float2 Pl[100 * PST];   // P[m][k]; later T[k][100]
  __shared__ float wr[4];
  __shared__ int wi[4];
  const int tid = threadIdx.x, ab = blockIdx.x;

  // un-pack radix-4 packed P into Pl[m*PST + k]
  for (int h = 0; h < 2; ++h) {
    const int v = h * 256 + tid;
    if (v < 425) {
      const int mp = v % 25, c = v / 25, kk = 3 * c;
      const float4* s4 = (const float4*)(P2 + (size_t)ab * 5100 + v * 12);
#pragma unroll
      for (int i = 0; i < 3; ++i) {
        float4 q01 = s4[i * 2], q23 = s4[i * 2 + 1];
        Pl[(mp     ) * PST + kk + i] = make_float2(q01.x, q01.y);
        Pl[(mp + 25) * PST + kk + i] = make_float2(q01.z, q01.w);
        Pl[(mp + 50) * PST + kk + i] = make_float2(q23.x, q23.y);
        Pl[(mp + 75) * PST + kk + i] = make_float2(q23.z, q23.w);
      }
    }
  }
  __syncthreads();

  // stage 1 radix-4: T[rp+25t][k] = sum_j i^{tj} (c1^j Q_j[k]),
  // Q_j[k] = sum_s P[4s+j][k] e^{+i 4 phi s rp}
  const int rp = tid % 25, kc = tid / 25;   // kc in [0,8), tid<200
  const int k0 = (kc < 3) ? 7 * kc : 21 + 6 * (kc - 3);
  const int CW = (kc < 3) ? 7 : 6;
  float Q0x[7], Q0y[7], Q1x[7], Q1y[7], Q2x[7], Q2y[7], Q3x[7], Q3y[7];
  if (tid < 200) {
#pragma unroll
    for (int q = 0; q < 7; ++q) {
      Q0x[q] = 0.f; Q0y[q] = 0.f; Q1x[q] = 0.f; Q1y[q] = 0.f;
      Q2x[q] = 0.f; Q2y[q] = 0.f; Q3x[q] = 0.f; Q3y[q] = 0.f;
    }
    float s4x, s4y;                          // step e^{+i 4 phi rp}
    sincosf(PHI * (float)((4 * rp) % 100), &s4y, &s4x);
    float wx = 1.f, wy = 0.f;
    for (int s = 0; s < 25; ++s) {
      const float2* p0 = Pl + (4 * s) * PST + k0;
#pragma unroll
      for (int i = 0; i < 7; ++i) {
        float2 q;
        q = p0[i];           CMAC(q, wx, wy, Q0x[i], Q0y[i]);
        q = p0[PST + i];     CMAC(q, wx, wy, Q1x[i], Q1y[i]);
        q = p0[2*PST + i];   CMAC(q, wx, wy, Q2x[i], Q2y[i]);
        q = p0[3*PST + i];   CMAC(q, wx, wy, Q3x[i], Q3y[i]);
      }
      CROT(wx, wy, s4x, s4y);
    }
  }
  __syncthreads();   // ALL P reads done; safe to overwrite Pl with T
  if (tid < 200) {
    float c1x, c1y; sincosf(PHI * (float)rp, &c1y, &c1x);   // e^{+i phi rp}
    float c2x = fmaf(c1x, c1x, -c1y * c1y), c2y = 2.f * c1x * c1y;
    float c3x = fmaf(c2x, c1x, -c2y * c1y), c3y = fmaf(c2x, c1y, c2y * c1x);
#pragma unroll
    for (int i = 0; i < 7; ++i) {
      float u1x = fmaf(c1x, Q1x[i], -c1y * Q1y[i]);
      float u1y = fmaf(c1x, Q1y[i],  c1y * Q1x[i]);
      float u2x = fmaf(c2x, Q2x[i], -c2y * Q2y[i]);
      float u2y = fmaf(c2x, Q2y[i],  c2y * Q2x[i]);
      float u3x = fmaf(c3x, Q3x[i], -c3y * Q3y[i]);
      float u3y = fmaf(c3x, Q3y[i],  c3y * Q3x[i]);
      float Axx = Q0x[i] + u2x, Ayy = Q0y[i] + u2y;
      float Bxx = Q0x[i] - u2x, Byy = Q0y[i] - u2y;
      float Cxx = u1x + u3x,    Cyy = u1y + u3y;
      float Dxx = u1x - u3x,    Dyy = u1y - u3y;
      if (i < CW) {
        float2* Tk = Pl + (k0 + i) * NFULL;
        Tk[rp]      = make_float2(Axx + Cxx, Ayy + Cyy);
        Tk[rp + 25] = make_float2(Bxx - Dyy, Byy + Dxx);   // B + iD
        Tk[rp + 50] = make_float2(Axx - Cxx, Ayy - Cyy);
        Tk[rp + 75] = make_float2(Bxx + Dyy, Byy - Dxx);   // B - iD
      }
    }
  }
  __syncthreads();   // T[k][r] ready (transposed)

  // stage 2: radix-2 pairs (c, c+50) via even/odd k. Thread (cp, rc).
  // float4 T reads (rows and r0 are even float2 indices -> 16B aligned);
  // overrun cols for RW=24 chunks accumulate junk, discarded at write.
  float best = -3.4e38f;
  int bidx = 0x7fffffff;
  if (tid < 200) {
    const int cp = tid % 50, rc = tid / 50;
    const int r0 = (rc < 2) ? rc * 26 : 52 + (rc - 2) * 24;   // even
    const int RW = (rc < 2) ? 26 : 24;
    float e[26], o[26];
#pragma unroll
    for (int i = 0; i < 26; ++i) { e[i] = 0.f; o[i] = 0.f; }
    float stx, sty;
    sincosf(PHI * (float)((2 * cp) % 100), &sty, &stx);       // step e^{+2i phi c}
    { float wx = stx, wy = sty;                               // k=2 start
      for (int s = 1; s < 25; ++s) {
        const float4* tp4 = (const float4*)(Pl + (2 * s) * NFULL + r0);
#pragma unroll
        for (int ii = 0; ii < 13; ++ii) {
          float4 q = tp4[ii];
          e[2*ii]   = fmaf(q.x, wx, fmaf(-q.y, wy, e[2*ii]));
          e[2*ii+1] = fmaf(q.z, wx, fmaf(-q.w, wy, e[2*ii+1]));
        }
        CROT(wx, wy, stx, sty);
      } }
    { float wx, wy;
      sincosf(PHI * (float)cp, &wy, &wx);                     // k=1 start
      for (int s = 0; s < 25; ++s) {
        const float4* tp4 = (const float4*)(Pl + (2 * s + 1) * NFULL + r0);
#pragma unroll
        for (int ii = 0; ii < 13; ++ii) {
          float4 q = tp4[ii];
          o[2*ii]   = fmaf(q.x, wx, fmaf(-q.y, wy, o[2*ii]));
          o[2*ii+1] = fmaf(q.z, wx, fmaf(-q.w, wy, o[2*ii+1]));
        }
        CROT(wx, wy, stx, sty);
      } }
    float sgn = (cp & 1) ? -1.f : 1.f;
    const float2* T0  = Pl + r0;
    const float2* T50 = Pl + 50 * NFULL + r0;
    const int ys0 = cp + 50, ys1 = cp;
#pragma unroll
    for (int i = 0; i < 26; ++i)
      if (i < RW) {
        int r = r0 + i;
        float base = T0[i].x + sgn * T50[i].x;
        float X0 = fmaf(2.f, e[i] + o[i], base);   // c = cp
        float X1 = fmaf(2.f, e[i] - o[i], base);   // c = cp + 50
        int xs = r + 50; if (xs >= 100) xs -= 100;
        int f0 = xs * 100 + ys0, f1 = xs * 100 + ys1;
        if (X0 > best || (X0 == best && f0 < bidx)) { best = X0; bidx = f0; }
        if (X1 > best || (X1 == best && f1 < bidx)) { best = X1; bidx = f1; }
      }
  }
  // wave-level shuffle reduction (64 lanes), then cross-wave via 4-entry LDS
  for (int off = 32; off > 0; off >>= 1) {
    float ov = __shfl_down(best, off);
    int oi = __shfl_down(bidx, off);
    if (ov > best || (ov == best && oi < bidx)) { best = ov; bidx = oi; }
  }
  if ((tid & 63) == 0) { wr[tid >> 6] = best; wi[tid >> 6] = bidx; }
  __syncthreads();
  if (tid == 0) {
#pragma unroll
    for (int w = 1; w < 4; ++w) {
      if (wr[w] > best || (wr[w] == best && wi[w] < bidx)) { best = wr[w]; bidx = wi[w]; }
    }
    pval[ab] = best; pidx[ab] = (ab / NB) * 10000 + bidx;
  }
}

// ---------------- final per-batch reduction over 120 angles ----------------
__global__ void k_final(const float* __restrict__ pval,
                        const int* __restrict__ pidx, float* __restrict__ out) {
  int b = threadIdx.x;
  if (b >= NB) return;
  float best = -3.4e38f; int bidx = 0x7fffffff;
  for (int a = 0; a < NA; ++a) {
    float v = pval[a * NB + b]; int ix = pidx[a * NB + b];
    if (v > best || (v == best && ix < bidx)) { best = v; bidx = ix; }
  }
  int a = bidx / 10000, rr = bidx % 10000, x = rr / NFULL, y = rr % NFULL;
  out[b] = a * ASTEP;
  out[NB + b * 2 + 0] = (float)(x - L);
  out[NB + b * 2 + 1] = (float)(y - L);
}

extern "C" void kernel_launch(void* const* d_in, const int* in_sizes, int n_in,
                              void* d_out, int out_size, void* d_ws, size_t ws_size,
                              hipStream_t stream) {
  const float* receptor = (const float*)d_in[0];
  const float* ligand   = (const float*)d_in[1];
  const float* conv_w   = (const float*)d_in[2];
  const float* conv_b   = (const float*)d_in[3];
  const float* scorer_w = (const float*)d_in[4];
  // scorer_b (d_in[5]) is argmax-invariant: unused.
  float* ws = (float*)d_ws;
  float* rec_feat = ws + OFF_REC;
  float* lig_comb = ws + OFF_LIG;
  float2* F1      = (float2*)(ws + OFF_F1);
  float2* P2      = (float2*)(ws + OFF_P2);
  float* pval     = ws + OFF_PVAL;
  int*   pidx     = (int*)(ws + OFF_PIDX);
  float* out      = (float*)d_out;

  k_conv<<<(NB * NPIX + 255) / 256, 256, 0, stream>>>(
      receptor, ligand, conv_w, conv_b, scorer_w, rec_feat, lig_comb);
  k_fwd_rec<<<80, 256, 0, stream>>>(rec_feat, F1);
  k_fwd_prod<<<NA * NB, 256, 0, stream>>>(lig_comb, F1, P2);
  k_inv_argmax<<<NA * NB, 256, 0, stream>>>(P2, pval, pidx);
  k_final<<<1, 64, 0, stream>>>(pval, pidx, out);
}